// Round 9
// baseline (95.486 us; speedup 1.0000x reference)
//
#include <hip/hip_runtime.h>
#include <math.h>

// Problem constants (fixed by setup_inputs)
constexpr int Bc = 256, Sc = 1024, Dc = 32, Kc = 512;
constexpr int ST = 256;                      // s-rows per block (grid = 1024 = 4/CU)
constexpr float LOG2E    = 1.4426950408889634f;
constexpr float LN2      = 0.6931471805599453f;
constexpr float LOG_NORM = 29.40603306051f;  // D * 0.5 * log(2*pi)

typedef __attribute__((ext_vector_type(4))) float f32x4;

#if __has_builtin(__builtin_amdgcn_exp2f)
#define EXP2F(v) __builtin_amdgcn_exp2f(v)
#else
#define EXP2F(v) exp2f(v)
#endif
#if __has_builtin(__builtin_amdgcn_logf)
#define LOG2F(v) __builtin_amdgcn_logf(v)
#else
#define LOG2F(v) log2f(v)
#endif

// pack 2 f32 -> 2 e4m3 bytes; word_sel is a template constant.
template <bool HI>
__device__ __forceinline__ int pkfp8(float a, float b, int old) {
    return __builtin_amdgcn_cvt_pk_fp8_f32(a, b, old, HI);
}

// Swizzled LDS byte offset for fp8 means: row = k (32 B), chunk = 8B octet 0..3,
// XOR (row>>2)&3. Hot-loop b64 read pattern is phase-optimal (4 phases x 32 banks).
__device__ __forceinline__ int swz8(int row, int chunk) {
    return row * 32 + ((chunk ^ ((row >> 2) & 3)) << 3);
}

// Single fully-resident kernel: grid(Bc*Sc/ST)=1024 blocks of 256 (4 waves).
// Wave owns 64 s-rows = 4 x 16-row MFMA subtiles sharing each B-fragment.
//   acc = sum_k 2^((l_k-0.5*m2_k)*log2e) * 2^((x*log2e).mu_k)
//   nll = 0.5*x^2 + LOG_NORM + lse - ln2*log2(acc)
__global__ __launch_bounds__(256, 4)
void gm_all(const float* __restrict__ x, const float* __restrict__ logits,
            const float* __restrict__ means, float* __restrict__ out)
{
    __shared__ unsigned char mlds[Kc * 32];   // 16 KB e4m3 means, swizzled
    __shared__ float wlds[Kc];                //  2 KB unnormalized weights
    __shared__ float x2p[ST];                 //  1 KB per-row sum(x^2)
    __shared__ float red[8];

    const int tid  = threadIdx.x;
    const int lane = tid & 63;
    const int wid  = tid >> 6;
    const int b    = blockIdx.x >> 2;
    const int s0   = (blockIdx.x & 3) * ST;
    const int q    = lane >> 4;               // k-octet of contraction dim
    const int ln   = lane & 15;
    const int rw   = wid * 64;

    // ---- means rows (tid, tid+256): fp32 read -> m2 (exact) + fp8 LDS stage ----
    float l0, l1;
    #pragma unroll
    for (int rr = 0; rr < 2; ++rr) {
        const int row = tid + rr * 256;
        const float4* mp = (const float4*)(means + (size_t)row * Dc);
        float m2 = 0.f;
        #pragma unroll
        for (int c = 0; c < 4; ++c) {
            float4 va = mp[2 * c], vb = mp[2 * c + 1];
            m2 += va.x*va.x + va.y*va.y + va.z*va.z + va.w*va.w
                + vb.x*vb.x + vb.y*vb.y + vb.z*vb.z + vb.w*vb.w;
            int2 pk;
            pk.x = pkfp8<false>(va.x, va.y, 0);
            pk.x = pkfp8<true >(va.z, va.w, pk.x);
            pk.y = pkfp8<false>(vb.x, vb.y, 0);
            pk.y = pkfp8<true >(vb.z, vb.w, pk.y);
            *(int2*)&mlds[swz8(row, c)] = pk;
        }
        const float lg = logits[b * Kc + row];
        if (rr == 0) l0 = lg; else l1 = lg;
        wlds[row] = EXP2F((lg - 0.5f * m2) * LOG2E);
    }

    // ---- lse phase 1: block max ----
    float mx = fmaxf(l0, l1);
    #pragma unroll
    for (int off = 32; off >= 1; off >>= 1) mx = fmaxf(mx, __shfl_xor(mx, off));
    if (lane == 0) red[wid] = mx;

    // ---- x A-fragments (4 subtiles), fp8-packed in-register ----
    int2 A[4];
    #pragma unroll
    for (int t = 0; t < 4; ++t) {
        const int row = rw + 16 * t + ln;
        const float4* xp = (const float4*)(x + ((size_t)b * Sc + s0 + row) * Dc) + q * 2;
        float4 v0 = xp[0], v1 = xp[1];
        A[t].x = pkfp8<false>(v0.x * LOG2E, v0.y * LOG2E, 0);
        A[t].x = pkfp8<true >(v0.z * LOG2E, v0.w * LOG2E, A[t].x);
        A[t].y = pkfp8<false>(v1.x * LOG2E, v1.y * LOG2E, 0);
        A[t].y = pkfp8<true >(v1.z * LOG2E, v1.w * LOG2E, A[t].y);
        float p = v0.x*v0.x + v0.y*v0.y + v0.z*v0.z + v0.w*v0.w
                + v1.x*v1.x + v1.y*v1.y + v1.z*v1.z + v1.w*v1.w;
        p += __shfl_xor(p, 16); p += __shfl_xor(p, 32);
        if (q == 0) x2p[row] = p;
    }
    __syncthreads();

    // ---- lse phase 2: exp-sum partials (consumed after the main loop) ----
    const float mxb = fmaxf(fmaxf(red[0], red[1]), fmaxf(red[2], red[3]));
    float sm = EXP2F((l0 - mxb) * LOG2E) + EXP2F((l1 - mxb) * LOG2E);
    #pragma unroll
    for (int off = 32; off >= 1; off >>= 1) sm += __shfl_xor(sm, off);
    if (lane == 0) red[4 + wid] = sm;

    // ---- main loop: 32 iters, 4 MFMA + 16 exp2 per iter ----
    const f32x4 zero = {0.f, 0.f, 0.f, 0.f};
    const long a0 = *(const long*)&A[0];
    const long a1 = *(const long*)&A[1];
    const long a2 = *(const long*)&A[2];
    const long a3 = *(const long*)&A[3];
    float acc[4][4] = {};

    #pragma unroll 2
    for (int kt = 0; kt < 32; ++kt) {
        const int krow = kt * 16 + ln;
        const long  bfr = *(const long*)&mlds[swz8(krow, q)];
        const float wv  = wlds[krow];         // broadcast across q-groups
        f32x4 d0 = __builtin_amdgcn_mfma_f32_16x16x32_fp8_fp8(a0, bfr, zero, 0, 0, 0);
        f32x4 d1 = __builtin_amdgcn_mfma_f32_16x16x32_fp8_fp8(a1, bfr, zero, 0, 0, 0);
        f32x4 d2 = __builtin_amdgcn_mfma_f32_16x16x32_fp8_fp8(a2, bfr, zero, 0, 0, 0);
        f32x4 d3 = __builtin_amdgcn_mfma_f32_16x16x32_fp8_fp8(a3, bfr, zero, 0, 0, 0);
        #pragma unroll
        for (int r = 0; r < 4; ++r) {
            acc[0][r] = fmaf(wv, EXP2F(d0[r]), acc[0][r]);
            acc[1][r] = fmaf(wv, EXP2F(d1[r]), acc[1][r]);
            acc[2][r] = fmaf(wv, EXP2F(d2[r]), acc[2][r]);
            acc[3][r] = fmaf(wv, EXP2F(d3[r]), acc[3][r]);
        }
    }
    __syncthreads();                          // red[4..7] ready
    const float lse  = mxb + LN2 * LOG2F(red[4] + red[5] + red[6] + red[7]);
    const float base = LOG_NORM + lse;

    // ---- epilogue: reduce 16 k-columns (low-4 lane bits), write ----
    #pragma unroll
    for (int t = 0; t < 4; ++t) {
        #pragma unroll
        for (int r = 0; r < 4; ++r) {
            float v = acc[t][r];
            v += __shfl_xor(v, 1); v += __shfl_xor(v, 2);
            v += __shfl_xor(v, 4); v += __shfl_xor(v, 8);
            if (ln == 0) {
                const int row = rw + 16 * t + q * 4 + r;   // C/D row = quad*4+reg
                out[(size_t)b * Sc + s0 + row] =
                    0.5f * x2p[row] + base - LN2 * LOG2F(v);
            }
        }
    }
}

extern "C" void kernel_launch(void* const* d_in, const int* in_sizes, int n_in,
                              void* d_out, int out_size, void* d_ws, size_t ws_size,
                              hipStream_t stream) {
    const float* x      = (const float*)d_in[0];
    const float* logits = (const float*)d_in[1];
    const float* means  = (const float*)d_in[2];
    float* out = (float*)d_out;
    (void)in_sizes; (void)n_in; (void)out_size; (void)d_ws; (void)ws_size;

    hipLaunchKernelGGL(gm_all, dim3(Bc * (Sc / ST)), dim3(256), 0, stream,
                       x, logits, means, out);
}

// Round 10
// 88.935 us; speedup vs baseline: 1.0737x; 1.0737x over previous
//
#include <hip/hip_runtime.h>
#include <math.h>

// Problem constants (fixed by setup_inputs)
constexpr int Bc = 256, Sc = 1024, Dc = 32, Kc = 512;
constexpr int ST = 128;                      // s-rows per main block (measured best)
constexpr float LOG2E    = 1.4426950408889634f;
constexpr float LN2      = 0.6931471805599453f;
constexpr float LOG_NORM = 29.40603306051f;  // D * 0.5 * log(2*pi)

typedef __attribute__((ext_vector_type(4))) float f32x4;

#if __has_builtin(__builtin_amdgcn_exp2f)
#define EXP2F(v) __builtin_amdgcn_exp2f(v)
#else
#define EXP2F(v) exp2f(v)
#endif
#if __has_builtin(__builtin_amdgcn_logf)
#define LOG2F(v) __builtin_amdgcn_logf(v)
#else
#define LOG2F(v) log2f(v)
#endif

// pack 2 f32 -> 2 e4m3 bytes; word_sel is a template constant.
template <bool HI>
__device__ __forceinline__ int pkfp8(float a, float b, int old) {
    return __builtin_amdgcn_cvt_pk_fp8_f32(a, b, old, HI);
}

// Swizzled LDS byte offset for fp8 means: row = k (32 B), chunk = 8B octet 0..3,
// XOR (row>>2)&3. Hot-loop b64 reads are phase-optimal (4 phases x 32 banks).
__device__ __forceinline__ int swz8(int row, int chunk) {
    return row * 32 + ((chunk ^ ((row >> 2) & 3)) << 3);
}

// ---------------- tiny prep: means -> e4m3 + m2buf[512] ----------------
// grid(32) x 256; thread owns 2 consecutive floats (coalesced 8B reads).
__global__ __launch_bounds__(256)
void gm_m2f8(const float* __restrict__ means,
             unsigned short* __restrict__ mf8, float* __restrict__ m2buf)
{
    const int t  = blockIdx.x * 256 + threadIdx.x;   // 0..8191 (pairs)
    const float v0 = means[2 * t];
    const float v1 = means[2 * t + 1];
    mf8[t] = (unsigned short)(pkfp8<false>(v0, v1, 0) & 0xffff);
    float sq = v0 * v0 + v1 * v1;
    #pragma unroll
    for (int off = 1; off <= 8; off <<= 1) sq += __shfl_xor(sq, off);
    if ((threadIdx.x & 15) == 0) m2buf[t >> 4] = sq;   // 16 pair-threads per row
}

// ---------------- main kernel ----------------
// grid(2048), 256 threads = 4 waves; wave owns 32 s-rows (2 x 16-row subtiles).
// (256,8): VGPR<=64 target -> 8 waves/EU; LDS 18.5 KB -> 8 blocks/CU.
//   acc = sum_k 2^((l_k-0.5*m2_k)*log2e) * 2^((x*log2e).mu_k)
//   nll = 0.5*x^2 + LOG_NORM + lse - ln2*log2(acc)
__global__ __launch_bounds__(256, 8)
void gm_main(const float* __restrict__ x, const float* __restrict__ logits,
             const float* __restrict__ m2buf, const unsigned short* __restrict__ mf8,
             float* __restrict__ out)
{
    __shared__ unsigned char mlds[Kc * 32];   // 16 KB e4m3 means, swizzled
    __shared__ float wlds[Kc];                //  2 KB unnormalized weights
    __shared__ float x2p[ST];                 // 0.5 KB per-row sum(x^2)
    __shared__ float red[8];

    const int tid  = threadIdx.x;
    const int lane = tid & 63;
    const int wid  = tid >> 6;
    const int b    = blockIdx.x >> 3;
    const int s0   = (blockIdx.x & 7) * ST;
    const int q    = lane >> 4;               // k-octet of contraction dim
    const int ln   = lane & 15;
    const int rw   = wid * 32;

    // stage means: 16 KB coalesced copy (8B chunks) into swizzled layout
    {
        const unsigned long long* src = (const unsigned long long*)mf8;
        #pragma unroll
        for (int j = 0; j < 8; ++j) {
            const int c = tid + j * 256;       // 8B-chunk index 0..2047
            *(unsigned long long*)&mlds[swz8(c >> 2, c & 3)] = src[c];
        }
    }

    // in-block unnormalized weights + start of lse
    const float l0 = logits[b * Kc + tid];
    const float l1 = logits[b * Kc + tid + 256];
    wlds[tid]       = EXP2F((l0 - 0.5f * m2buf[tid])       * LOG2E);
    wlds[tid + 256] = EXP2F((l1 - 0.5f * m2buf[tid + 256]) * LOG2E);

    float mx = fmaxf(l0, l1);
    #pragma unroll
    for (int off = 32; off >= 1; off >>= 1) mx = fmaxf(mx, __shfl_xor(mx, off));
    if (lane == 0) red[wid] = mx;

    // x A-fragments direct from global; pack each subtile before the next
    // (short float4 live ranges -> lower prologue VGPR peak).
    const int row0 = rw + ln, row1 = row0 + 16;
    long a0, a1;
    {
        const float4* xp0 = (const float4*)(x + ((size_t)b * Sc + s0 + row0) * Dc) + q * 2;
        float4 v0 = xp0[0], v1 = xp0[1];
        int2 A;
        A.x = pkfp8<false>(v0.x * LOG2E, v0.y * LOG2E, 0);
        A.x = pkfp8<true >(v0.z * LOG2E, v0.w * LOG2E, A.x);
        A.y = pkfp8<false>(v1.x * LOG2E, v1.y * LOG2E, 0);
        A.y = pkfp8<true >(v1.z * LOG2E, v1.w * LOG2E, A.y);
        a0 = *(const long*)&A;
        float p = v0.x*v0.x + v0.y*v0.y + v0.z*v0.z + v0.w*v0.w
                + v1.x*v1.x + v1.y*v1.y + v1.z*v1.z + v1.w*v1.w;
        p += __shfl_xor(p, 16); p += __shfl_xor(p, 32);
        if (q == 0) x2p[row0] = p;
    }
    {
        const float4* xp1 = (const float4*)(x + ((size_t)b * Sc + s0 + row1) * Dc) + q * 2;
        float4 u0 = xp1[0], u1 = xp1[1];
        int2 A;
        A.x = pkfp8<false>(u0.x * LOG2E, u0.y * LOG2E, 0);
        A.x = pkfp8<true >(u0.z * LOG2E, u0.w * LOG2E, A.x);
        A.y = pkfp8<false>(u1.x * LOG2E, u1.y * LOG2E, 0);
        A.y = pkfp8<true >(u1.z * LOG2E, u1.w * LOG2E, A.y);
        a1 = *(const long*)&A;
        float p = u0.x*u0.x + u0.y*u0.y + u0.z*u0.z + u0.w*u0.w
                + u1.x*u1.x + u1.y*u1.y + u1.z*u1.z + u1.w*u1.w;
        p += __shfl_xor(p, 16); p += __shfl_xor(p, 32);
        if (q == 0) x2p[row1] = p;
    }
    __syncthreads();

    // finish lse (max across waves parked in red[0..3])
    const float mxb = fmaxf(fmaxf(red[0], red[1]), fmaxf(red[2], red[3]));
    float sm = EXP2F((l0 - mxb) * LOG2E) + EXP2F((l1 - mxb) * LOG2E);
    #pragma unroll
    for (int off = 32; off >= 1; off >>= 1) sm += __shfl_xor(sm, off);
    if (lane == 0) red[4 + wid] = sm;

    // main loop; swizzle XOR term is kt-invariant: addr = base + kt*512
    const int bbase = ln * 32 + ((q ^ ((ln >> 2) & 3)) << 3);
    const f32x4 zero = {0.f, 0.f, 0.f, 0.f};
    float acc0[4] = {0.f, 0.f, 0.f, 0.f};
    float acc1[4] = {0.f, 0.f, 0.f, 0.f};

    #pragma unroll 4
    for (int kt = 0; kt < 32; ++kt) {
        const long  bfr = *(const long*)&mlds[bbase + kt * 512];
        const float wv  = wlds[kt * 16 + ln];  // bcast across q-groups
        f32x4 d0 = __builtin_amdgcn_mfma_f32_16x16x32_fp8_fp8(a0, bfr, zero, 0, 0, 0);
        f32x4 d1 = __builtin_amdgcn_mfma_f32_16x16x32_fp8_fp8(a1, bfr, zero, 0, 0, 0);
        #pragma unroll
        for (int r = 0; r < 4; ++r) {
            acc0[r] = fmaf(wv, EXP2F(d0[r]), acc0[r]);
            acc1[r] = fmaf(wv, EXP2F(d1[r]), acc1[r]);
        }
    }
    __syncthreads();                          // red[4..7] ready
    const float lse  = mxb + LN2 * LOG2F(red[4] + red[5] + red[6] + red[7]);
    const float base = LOG_NORM + lse;

    // reduce over the 16 k-columns (low-4 lane bits), then write
    #pragma unroll
    for (int r = 0; r < 4; ++r) {
        float s0v = acc0[r], s1v = acc1[r];
        s0v += __shfl_xor(s0v, 1); s0v += __shfl_xor(s0v, 2);
        s0v += __shfl_xor(s0v, 4); s0v += __shfl_xor(s0v, 8);
        s1v += __shfl_xor(s1v, 1); s1v += __shfl_xor(s1v, 2);
        s1v += __shfl_xor(s1v, 4); s1v += __shfl_xor(s1v, 8);
        if (ln == 0) {
            const int r0 = rw + q * 4 + r;       // C/D row = quad*4 + reg
            const int r1 = r0 + 16;
            out[(size_t)b * Sc + s0 + r0] = 0.5f * x2p[r0] + base - LN2 * LOG2F(s0v);
            out[(size_t)b * Sc + s0 + r1] = 0.5f * x2p[r1] + base - LN2 * LOG2F(s1v);
        }
    }
}

extern "C" void kernel_launch(void* const* d_in, const int* in_sizes, int n_in,
                              void* d_out, int out_size, void* d_ws, size_t ws_size,
                              hipStream_t stream) {
    const float* x      = (const float*)d_in[0];
    const float* logits = (const float*)d_in[1];
    const float* means  = (const float*)d_in[2];
    float* out = (float*)d_out;
    (void)in_sizes; (void)n_in; (void)out_size; (void)ws_size;

    unsigned short* mf8   = (unsigned short*)d_ws;             // 16 KB (8192 u16)
    float*          m2buf = (float*)((char*)d_ws + 16384);     //  2 KB

    hipLaunchKernelGGL(gm_m2f8, dim3(32), dim3(256), 0, stream, means, mf8, m2buf);
    hipLaunchKernelGGL(gm_main, dim3(Bc * (Sc / ST)), dim3(256), 0, stream,
                       x, logits, m2buf, mf8, out);
}